// Round 3
// baseline (3232.681 us; speedup 1.0000x reference)
//
#include <hip/hip_runtime.h>
#include <cmath>

// ---------------------------------------------------------------------------
// GCN 3-layer forward on MI355X.
// Pipeline per layer: h = in @ W  (fp32 vector GEMM, W staged in LDS)
//                     agg = h*dinv^2 + b (self-loop + bias, also zero-init)
//                     agg[dst] += h[src]*dinv[src]*dinv[dst]  (edge scatter, HW f32 atomics)
// ReLU folded into next GEMM's load. Final log_softmax, wave per node.
// ---------------------------------------------------------------------------

__global__ void k_init_deg(float* deg, int n) {
    int i = blockIdx.x * blockDim.x + threadIdx.x;
    if (i < n) deg[i] = 1.0f;   // self-loop contributes 1
}

__global__ void k_count_deg(const int* __restrict__ dst, float* deg, int e) {
    int i = blockIdx.x * blockDim.x + threadIdx.x;
    int stride = gridDim.x * blockDim.x;
    for (; i < e; i += stride) unsafeAtomicAdd(&deg[dst[i]], 1.0f);
}

__global__ void k_rsqrt(float* deg, int n) {
    int i = blockIdx.x * blockDim.x + threadIdx.x;
    if (i < n) deg[i] = rsqrtf(deg[i]);   // deg >= 1 always (self-loops)
}

// GEMM: out[N x FOUT] = (RELU? relu(in) : in)[N x 128] @ W[128 x FOUT]
// block = 256 threads, 32 rows per block. W fully staged in LDS.
template<int FOUT, bool RELU>
__global__ __launch_bounds__(256) void k_gemm(const float* __restrict__ in,
                                              const float* __restrict__ W,
                                              float* __restrict__ out, int n) {
    __shared__ float Ws[128 * FOUT];
    __shared__ float Xs[32][129];   // +1 pad: conflict-free a-loads
    const int tid = threadIdx.x;
    const int row0 = blockIdx.x * 32;

    // stage W (vectorized)
    for (int i = tid; i < 128 * FOUT / 4; i += 256)
        ((float4*)Ws)[i] = ((const float4*)W)[i];

    // stage X tile (32 rows x 128), relu on load if requested
    for (int i = tid; i < 1024; i += 256) {
        int r = i >> 5;
        int c = (i & 31) << 2;
        int gr = row0 + r;
        float4 v;
        if (gr < n) v = *(const float4*)(in + (size_t)gr * 128 + c);
        else        v = make_float4(0.f, 0.f, 0.f, 0.f);
        if (RELU) {
            v.x = fmaxf(v.x, 0.f); v.y = fmaxf(v.y, 0.f);
            v.z = fmaxf(v.z, 0.f); v.w = fmaxf(v.w, 0.f);
        }
        Xs[r][c + 0] = v.x; Xs[r][c + 1] = v.y;
        Xs[r][c + 2] = v.z; Xs[r][c + 3] = v.w;
    }
    __syncthreads();

    if constexpr (FOUT == 128) {
        // 16x16 thread grid: 2 rows x 8 cols per thread
        const int tc = (tid & 15) * 8;
        const int tr = (tid >> 4) * 2;
        float acc0[8] = {0,0,0,0,0,0,0,0};
        float acc1[8] = {0,0,0,0,0,0,0,0};
        for (int k = 0; k < 128; ++k) {
            float a0 = Xs[tr][k];
            float a1 = Xs[tr + 1][k];
            float4 b0 = *(const float4*)&Ws[k * 128 + tc];
            float4 b1 = *(const float4*)&Ws[k * 128 + tc + 4];
            acc0[0] += a0 * b0.x; acc0[1] += a0 * b0.y;
            acc0[2] += a0 * b0.z; acc0[3] += a0 * b0.w;
            acc0[4] += a0 * b1.x; acc0[5] += a0 * b1.y;
            acc0[6] += a0 * b1.z; acc0[7] += a0 * b1.w;
            acc1[0] += a1 * b0.x; acc1[1] += a1 * b0.y;
            acc1[2] += a1 * b0.z; acc1[3] += a1 * b0.w;
            acc1[4] += a1 * b1.x; acc1[5] += a1 * b1.y;
            acc1[6] += a1 * b1.z; acc1[7] += a1 * b1.w;
        }
        int gr = row0 + tr;
        if (gr < n) {
            *(float4*)(out + (size_t)gr * 128 + tc)     = make_float4(acc0[0], acc0[1], acc0[2], acc0[3]);
            *(float4*)(out + (size_t)gr * 128 + tc + 4) = make_float4(acc0[4], acc0[5], acc0[6], acc0[7]);
        }
        if (gr + 1 < n) {
            *(float4*)(out + (size_t)(gr + 1) * 128 + tc)     = make_float4(acc1[0], acc1[1], acc1[2], acc1[3]);
            *(float4*)(out + (size_t)(gr + 1) * 128 + tc + 4) = make_float4(acc1[4], acc1[5], acc1[6], acc1[7]);
        }
    } else {
        // FOUT == 40: 32 thread-rows x 8 thread-cols, 1 row x 5 cols per thread
        const int tc = (tid & 7) * 5;
        const int tr = tid >> 3;
        float acc[5] = {0,0,0,0,0};
        for (int k = 0; k < 128; ++k) {
            float a = Xs[tr][k];
            #pragma unroll
            for (int j = 0; j < 5; ++j) acc[j] += a * Ws[k * 40 + tc + j];
        }
        int gr = row0 + tr;
        if (gr < n) {
            #pragma unroll
            for (int j = 0; j < 5; ++j) out[(size_t)gr * 40 + tc + j] = acc[j];
        }
    }
}

// agg[i][f] = h[i][f]*dinv[i]^2 + b[f]  (self-loop message + bias; full init)
template<int F>
__global__ void k_self_init(const float* __restrict__ h, const float* __restrict__ dinv,
                            const float* __restrict__ b, float* __restrict__ agg, int n) {
    size_t total = (size_t)n * F;
    size_t stride = (size_t)gridDim.x * blockDim.x;
    for (size_t i = (size_t)blockIdx.x * blockDim.x + threadIdx.x; i < total; i += stride) {
        int node = (int)(i / F);
        int f    = (int)(i % F);
        float d = dinv[node];
        agg[i] = h[i] * d * d + b[f];
    }
}

// one wave per edge, lane handles 2 features (float2)
__global__ void k_edge_agg128(const int* __restrict__ src, const int* __restrict__ dst,
                              const float* __restrict__ dinv, const float* __restrict__ h,
                              float* agg, int e) {
    int gtid = blockIdx.x * blockDim.x + threadIdx.x;
    int wave = gtid >> 6;
    int lane = gtid & 63;
    int nw = (gridDim.x * blockDim.x) >> 6;
    for (int i = wave; i < e; i += nw) {
        int s = src[i], d = dst[i];
        float nm = dinv[s] * dinv[d];
        float2 v = *(const float2*)(h + (size_t)s * 128 + lane * 2);
        float* ap = agg + (size_t)d * 128 + lane * 2;
        unsafeAtomicAdd(ap,     v.x * nm);
        unsafeAtomicAdd(ap + 1, v.y * nm);
    }
}

// one wave per edge, lanes 0..39 active
__global__ void k_edge_agg40(const int* __restrict__ src, const int* __restrict__ dst,
                             const float* __restrict__ dinv, const float* __restrict__ h,
                             float* agg, int e) {
    int gtid = blockIdx.x * blockDim.x + threadIdx.x;
    int wave = gtid >> 6;
    int lane = gtid & 63;
    int nw = (gridDim.x * blockDim.x) >> 6;
    for (int i = wave; i < e; i += nw) {
        int s = src[i], d = dst[i];
        float nm = dinv[s] * dinv[d];
        if (lane < 40) {
            float v = h[(size_t)s * 40 + lane];
            unsafeAtomicAdd(agg + (size_t)d * 40 + lane, v * nm);
        }
    }
}

// wave per node; lanes 0..39 hold the row
__global__ void k_logsoftmax(const float* __restrict__ in, float* __restrict__ out, int n) {
    int gtid = blockIdx.x * blockDim.x + threadIdx.x;
    int node = gtid >> 6;
    int lane = gtid & 63;
    if (node >= n) return;
    float v = (lane < 40) ? in[(size_t)node * 40 + lane] : -3.4e38f;
    float m = v;
    #pragma unroll
    for (int off = 32; off; off >>= 1) m = fmaxf(m, __shfl_xor(m, off, 64));
    float ex = (lane < 40) ? expf(v - m) : 0.f;
    float s = ex;
    #pragma unroll
    for (int off = 32; off; off >>= 1) s += __shfl_xor(s, off, 64);
    if (lane < 40) out[(size_t)node * 40 + lane] = v - m - logf(s);
}

extern "C" void kernel_launch(void* const* d_in, const int* in_sizes, int n_in,
                              void* d_out, int out_size, void* d_ws, size_t ws_size,
                              hipStream_t stream) {
    const float* x  = (const float*)d_in[0];
    const int*   ei = (const int*)d_in[1];
    const float* W1 = (const float*)d_in[2];
    const float* b1 = (const float*)d_in[3];
    const float* W2 = (const float*)d_in[4];
    const float* b2 = (const float*)d_in[5];
    const float* W3 = (const float*)d_in[6];
    const float* b3 = (const float*)d_in[7];
    float* out = (float*)d_out;

    const int N = in_sizes[0] / 128;
    const int E = in_sizes[1] / 2;
    const int* src = ei;
    const int* dst = ei + E;

    float* dinv = (float*)d_ws;            // N floats (deg -> dinv in place)
    float* h    = dinv + 50176;            // N*128 floats (aligned)
    float* ag   = h + (size_t)N * 128;     // N*128 floats

    const int nblk = (N + 255) / 256;
    const int gemm_grid = (N + 31) / 32;

    // --- degree / normalization ---
    k_init_deg<<<nblk, 256, 0, stream>>>(dinv, N);
    k_count_deg<<<2048, 256, 0, stream>>>(dst, dinv, E);
    k_rsqrt<<<nblk, 256, 0, stream>>>(dinv, N);

    // --- layer 1 ---
    k_gemm<128, false><<<gemm_grid, 256, 0, stream>>>(x, W1, h, N);
    k_self_init<128><<<2048, 256, 0, stream>>>(h, dinv, b1, ag, N);
    k_edge_agg128<<<2048, 256, 0, stream>>>(src, dst, dinv, h, ag, E);

    // --- layer 2 (relu on load) ---
    k_gemm<128, true><<<gemm_grid, 256, 0, stream>>>(ag, W2, h, N);
    k_self_init<128><<<2048, 256, 0, stream>>>(h, dinv, b2, ag, N);
    k_edge_agg128<<<2048, 256, 0, stream>>>(src, dst, dinv, h, ag, E);

    // --- layer 3 (relu on load, 40 outputs) ---
    k_gemm<40, true><<<gemm_grid, 256, 0, stream>>>(ag, W3, h, N);
    k_self_init<40><<<2048, 256, 0, stream>>>(h, dinv, b3, ag, N);
    k_edge_agg40<<<2048, 256, 0, stream>>>(src, dst, dinv, h, ag, E);

    // --- log_softmax ---
    k_logsoftmax<<<(N * 64 + 255) / 256, 256, 0, stream>>>(ag, out, N);
}

// Round 8
// 857.209 us; speedup vs baseline: 3.7712x; 3.7712x over previous
//
#include <hip/hip_runtime.h>
#include <cmath>

// ---------------------------------------------------------------------------
// GCN 3-layer forward on MI355X — round 4: atomic-free aggregation via
// on-device counting sort (dst -> CSR). One wave per destination node,
// register accumulation, single coalesced write. Self-loop+bias+ReLU fused
// into agg write; log_softmax fused into layer-3 agg.
//   out[d] = (sum_e h[src]*dinv[src] + h[d]*dinv[d]) * dinv[d] + b
// ---------------------------------------------------------------------------

__global__ void k_hist(const int* __restrict__ dst, int* __restrict__ hist, int e) {
    int i = blockIdx.x * blockDim.x + threadIdx.x;
    int stride = gridDim.x * blockDim.x;
    for (; i < e; i += stride) atomicAdd(&hist[dst[i]], 1);
}

// single-block exclusive scan of hist[n] -> row_start[n]
__global__ __launch_bounds__(1024) void k_scan(const int* __restrict__ hist,
                                               int* __restrict__ row_start, int n) {
    __shared__ int lds[1024];
    const int tid = threadIdx.x;
    const int ch = (n + 1023) >> 10;
    const int base = tid * ch;
    const int end = (base + ch < n) ? base + ch : n;
    int sum = 0;
    for (int j = base; j < end; ++j) sum += hist[j];
    lds[tid] = sum;
    __syncthreads();
    // Hillis-Steele inclusive scan
    for (int off = 1; off < 1024; off <<= 1) {
        int t = (tid >= off) ? lds[tid - off] : 0;
        __syncthreads();
        lds[tid] += t;
        __syncthreads();
    }
    int run = lds[tid] - sum;   // exclusive offset
    for (int j = base; j < end; ++j) {
        row_start[j] = run;
        run += hist[j];
    }
}

// dinv = rsqrt(1 + deg); cursor = copy of row_start (scatter increments it;
// after scatter cursor[i] == row_end[i])
__global__ void k_dinv(const int* __restrict__ hist, const int* __restrict__ row_start,
                       float* __restrict__ dinv, int* __restrict__ cursor, int n) {
    int i = blockIdx.x * blockDim.x + threadIdx.x;
    if (i < n) {
        dinv[i] = rsqrtf(1.0f + (float)hist[i]);
        cursor[i] = row_start[i];
    }
}

__global__ void k_scatter(const int* __restrict__ src, const int* __restrict__ dst,
                          int* __restrict__ cursor, unsigned short* __restrict__ ssrc, int e) {
    int i = blockIdx.x * blockDim.x + threadIdx.x;
    int stride = gridDim.x * blockDim.x;
    for (; i < e; i += stride) {
        int pos = atomicAdd(&cursor[dst[i]], 1);
        ssrc[pos] = (unsigned short)src[i];
    }
}

// GEMM: out[N x FOUT] = in[N x 128] @ W[128 x FOUT]; W staged in LDS.
template<int FOUT>
__global__ __launch_bounds__(256) void k_gemm(const float* __restrict__ in,
                                              const float* __restrict__ W,
                                              float* __restrict__ out, int n) {
    __shared__ float Ws[128 * FOUT];
    __shared__ float Xs[32][129];
    const int tid = threadIdx.x;
    const int row0 = blockIdx.x * 32;

    for (int i = tid; i < 128 * FOUT / 4; i += 256)
        ((float4*)Ws)[i] = ((const float4*)W)[i];

    for (int i = tid; i < 1024; i += 256) {
        int r = i >> 5;
        int c = (i & 31) << 2;
        int gr = row0 + r;
        float4 v = make_float4(0.f, 0.f, 0.f, 0.f);
        if (gr < n) v = *(const float4*)(in + (size_t)gr * 128 + c);
        Xs[r][c + 0] = v.x; Xs[r][c + 1] = v.y;
        Xs[r][c + 2] = v.z; Xs[r][c + 3] = v.w;
    }
    __syncthreads();

    if constexpr (FOUT == 128) {
        const int tc = (tid & 15) * 8;
        const int tr = (tid >> 4) * 2;
        float acc0[8] = {0,0,0,0,0,0,0,0};
        float acc1[8] = {0,0,0,0,0,0,0,0};
        for (int k = 0; k < 128; ++k) {
            float a0 = Xs[tr][k];
            float a1 = Xs[tr + 1][k];
            float4 b0 = *(const float4*)&Ws[k * 128 + tc];
            float4 b1 = *(const float4*)&Ws[k * 128 + tc + 4];
            acc0[0] += a0 * b0.x; acc0[1] += a0 * b0.y;
            acc0[2] += a0 * b0.z; acc0[3] += a0 * b0.w;
            acc0[4] += a0 * b1.x; acc0[5] += a0 * b1.y;
            acc0[6] += a0 * b1.z; acc0[7] += a0 * b1.w;
            acc1[0] += a1 * b0.x; acc1[1] += a1 * b0.y;
            acc1[2] += a1 * b0.z; acc1[3] += a1 * b0.w;
            acc1[4] += a1 * b1.x; acc1[5] += a1 * b1.y;
            acc1[6] += a1 * b1.z; acc1[7] += a1 * b1.w;
        }
        int gr = row0 + tr;
        if (gr < n) {
            *(float4*)(out + (size_t)gr * 128 + tc)     = make_float4(acc0[0], acc0[1], acc0[2], acc0[3]);
            *(float4*)(out + (size_t)gr * 128 + tc + 4) = make_float4(acc0[4], acc0[5], acc0[6], acc0[7]);
        }
        if (gr + 1 < n) {
            *(float4*)(out + (size_t)(gr + 1) * 128 + tc)     = make_float4(acc1[0], acc1[1], acc1[2], acc1[3]);
            *(float4*)(out + (size_t)(gr + 1) * 128 + tc + 4) = make_float4(acc1[4], acc1[5], acc1[6], acc1[7]);
        }
    } else {
        const int tc = (tid & 7) * 5;
        const int tr = tid >> 3;
        float acc[5] = {0,0,0,0,0};
        for (int k = 0; k < 128; ++k) {
            float a = Xs[tr][k];
            #pragma unroll
            for (int j = 0; j < 5; ++j) acc[j] += a * Ws[k * 40 + tc + j];
        }
        int gr = row0 + tr;
        if (gr < n) {
            #pragma unroll
            for (int j = 0; j < 5; ++j) out[(size_t)gr * 40 + tc + j] = acc[j];
        }
    }
}

// CSR aggregation, 128 features: one wave per dst node, lane owns 2 features.
template<bool RELU>
__global__ __launch_bounds__(256) void k_agg128(const int* __restrict__ row_start,
                                                const int* __restrict__ row_end,
                                                const unsigned short* __restrict__ ssrc,
                                                const float* __restrict__ dinv,
                                                const float* __restrict__ h,
                                                const float* __restrict__ bias,
                                                float* __restrict__ ag, int n) {
    const int wid = (blockIdx.x * 256 + threadIdx.x) >> 6;
    const int lane = threadIdx.x & 63;
    if (wid >= n) return;
    const int d = wid;
    const int beg = row_start[d];
    const int end = row_end[d];
    const int f = lane * 2;

    float ax = 0.f, ay = 0.f;
    int i = beg;
    for (; i + 2 <= end; i += 2) {
        int s0 = ssrc[i];
        int s1 = ssrc[i + 1];
        float w0 = dinv[s0];
        float w1 = dinv[s1];
        float2 v0 = *(const float2*)(h + (size_t)s0 * 128 + f);
        float2 v1 = *(const float2*)(h + (size_t)s1 * 128 + f);
        ax += v0.x * w0 + v1.x * w1;
        ay += v0.y * w0 + v1.y * w1;
    }
    if (i < end) {
        int s = ssrc[i];
        float w = dinv[s];
        float2 v = *(const float2*)(h + (size_t)s * 128 + f);
        ax += v.x * w;
        ay += v.y * w;
    }
    const float dd = dinv[d];
    float2 hv = *(const float2*)(h + (size_t)d * 128 + f);
    float ox = (ax + hv.x * dd) * dd + bias[f];
    float oy = (ay + hv.y * dd) * dd + bias[f + 1];
    if (RELU) { ox = fmaxf(ox, 0.f); oy = fmaxf(oy, 0.f); }
    *(float2*)(ag + (size_t)d * 128 + f) = make_float2(ox, oy);
}

// CSR aggregation, 40 features + fused log_softmax. Wave per node, lanes 0..39.
__global__ __launch_bounds__(256) void k_agg40_lsm(const int* __restrict__ row_start,
                                                   const int* __restrict__ row_end,
                                                   const unsigned short* __restrict__ ssrc,
                                                   const float* __restrict__ dinv,
                                                   const float* __restrict__ h,
                                                   const float* __restrict__ bias,
                                                   float* __restrict__ out, int n) {
    const int wid = (blockIdx.x * 256 + threadIdx.x) >> 6;
    const int lane = threadIdx.x & 63;
    if (wid >= n) return;
    const int d = wid;
    const int beg = row_start[d];
    const int end = row_end[d];
    const bool act = lane < 40;
    const int f = act ? lane : 0;

    float acc = 0.f;
    int i = beg;
    for (; i + 2 <= end; i += 2) {
        int s0 = ssrc[i];
        int s1 = ssrc[i + 1];
        float w0 = dinv[s0];
        float w1 = dinv[s1];
        acc += h[(size_t)s0 * 40 + f] * w0 + h[(size_t)s1 * 40 + f] * w1;
    }
    if (i < end) {
        int s = ssrc[i];
        acc += h[(size_t)s * 40 + f] * dinv[s];
    }
    const float dd = dinv[d];
    float v = (acc + h[(size_t)d * 40 + f] * dd) * dd + bias[f];

    // log_softmax across lanes 0..39
    float m = act ? v : -3.4e38f;
    #pragma unroll
    for (int off = 32; off; off >>= 1) m = fmaxf(m, __shfl_xor(m, off, 64));
    float ex = act ? __expf(v - m) : 0.f;
    float s = ex;
    #pragma unroll
    for (int off = 32; off; off >>= 1) s += __shfl_xor(s, off, 64);
    if (act) out[(size_t)d * 40 + lane] = v - m - logf(s);
}

extern "C" void kernel_launch(void* const* d_in, const int* in_sizes, int n_in,
                              void* d_out, int out_size, void* d_ws, size_t ws_size,
                              hipStream_t stream) {
    const float* x  = (const float*)d_in[0];
    const int*   ei = (const int*)d_in[1];
    const float* W1 = (const float*)d_in[2];
    const float* b1 = (const float*)d_in[3];
    const float* W2 = (const float*)d_in[4];
    const float* b2 = (const float*)d_in[5];
    const float* W3 = (const float*)d_in[6];
    const float* b3 = (const float*)d_in[7];
    float* out = (float*)d_out;

    const int N = in_sizes[0] / 128;
    const int E = in_sizes[1] / 2;
    const int* src = ei;
    const int* dst = ei + E;

    // workspace layout (float-sized slots, regions 256-aligned)
    float* ws = (float*)d_ws;
    const int NP = 50176;                       // N padded
    float*          dinv      = ws;                            // NP floats
    int*            hist      = (int*)(ws + NP);               // NP ints
    int*            row_start = (int*)(ws + 2 * NP);           // NP ints
    int*            cursor    = (int*)(ws + 3 * NP);           // NP ints
    unsigned short* ssrc      = (unsigned short*)(ws + 4 * NP);// E uint16 = E/2 floats
    float*          h         = ws + 4 * NP + (E + 2) / 2 + 62;// N*128
    float*          ag        = h + (size_t)N * 128;           // N*128

    const int nblk = (N + 255) / 256;
    const int gemm_grid = (N + 31) / 32;
    const int agg_grid = (N + 3) / 4;   // 4 waves (nodes) per 256-block

    // --- build CSR (dst-sorted) + degree norm ---
    hipMemsetAsync(hist, 0, (size_t)N * sizeof(int), stream);
    k_hist<<<1024, 256, 0, stream>>>(dst, hist, E);
    k_scan<<<1, 1024, 0, stream>>>(hist, row_start, N);
    k_dinv<<<nblk, 256, 0, stream>>>(hist, row_start, dinv, cursor, N);
    k_scatter<<<1024, 256, 0, stream>>>(src, dst, cursor, ssrc, E);
    // cursor[i] now == row_end[i]

    // --- layer 1 ---
    k_gemm<128><<<gemm_grid, 256, 0, stream>>>(x, W1, h, N);
    k_agg128<true><<<agg_grid, 256, 0, stream>>>(row_start, cursor, ssrc, dinv, h, b1, ag, N);

    // --- layer 2 ---
    k_gemm<128><<<gemm_grid, 256, 0, stream>>>(ag, W2, h, N);
    k_agg128<true><<<agg_grid, 256, 0, stream>>>(row_start, cursor, ssrc, dinv, h, b2, ag, N);

    // --- layer 3 + log_softmax ---
    k_gemm<40><<<gemm_grid, 256, 0, stream>>>(ag, W3, h, N);
    k_agg40_lsm<<<agg_grid, 256, 0, stream>>>(row_start, cursor, ssrc, dinv, h, b3, out, N);
}

// Round 10
// 792.978 us; speedup vs baseline: 4.0766x; 1.0810x over previous
//
#include <hip/hip_runtime.h>
#include <cmath>

// ---------------------------------------------------------------------------
// GCN 3-layer forward on MI355X — round 9.
// vs round 8 (857us): (1) h stored bf16 -> halves gather bytes in agg
// (agg was 45% HBM-path-bound, FETCH 438MB); (2) multi-pass dst-range
// scatter to kill 64B-line write amplification (WRITE 114MB for 3.4MB
// payload); (3) dinv/cursor folded into scan (one fewer launch).
// ---------------------------------------------------------------------------

typedef unsigned short ushort_t;

__device__ __forceinline__ ushort_t f2bf(float x) {
    unsigned int u = __float_as_uint(x);
    u += 0x7FFF + ((u >> 16) & 1);   // round-to-nearest-even
    return (ushort_t)(u >> 16);
}
__device__ __forceinline__ float bf2f(ushort_t b) {
    return __uint_as_float(((unsigned int)b) << 16);
}

__global__ void k_hist(const int* __restrict__ dst, int* __restrict__ hist, int e) {
    int i = blockIdx.x * blockDim.x + threadIdx.x;
    int stride = gridDim.x * blockDim.x;
    for (; i < e; i += stride) atomicAdd(&hist[dst[i]], 1);
}

// single-block: exclusive scan of hist -> row_start, cursor copy, dinv
__global__ __launch_bounds__(1024) void k_scan(const int* __restrict__ hist,
                                               int* __restrict__ row_start,
                                               int* __restrict__ cursor,
                                               float* __restrict__ dinv, int n) {
    __shared__ int lds[1024];
    const int tid = threadIdx.x;
    const int ch = (n + 1023) >> 10;
    const int base = tid * ch;
    const int end = (base + ch < n) ? base + ch : n;
    int sum = 0;
    for (int j = base; j < end; ++j) sum += hist[j];
    lds[tid] = sum;
    __syncthreads();
    for (int off = 1; off < 1024; off <<= 1) {
        int t = (tid >= off) ? lds[tid - off] : 0;
        __syncthreads();
        lds[tid] += t;
        __syncthreads();
    }
    int run = lds[tid] - sum;   // exclusive offset
    for (int j = base; j < end; ++j) {
        int hj = hist[j];
        row_start[j] = run;
        cursor[j] = run;
        dinv[j] = rsqrtf(1.0f + (float)hj);
        run += hj;
    }
}

// multi-pass scatter: pass p handles dst in [p*8192,(p+1)*8192) so concurrent
// ssrc writes are confined to a ~512KB window (L2 lines fill before eviction).
__global__ void k_scatter(const int* __restrict__ src, const int* __restrict__ dst,
                          int* __restrict__ cursor, ushort_t* __restrict__ ssrc, int e) {
    const int tid0 = blockIdx.x * blockDim.x + threadIdx.x;
    const int stride = gridDim.x * blockDim.x;
    for (int p = 0; p < 7; ++p) {          // 50000>>13 == 6, so passes 0..6
        for (int i = tid0; i < e; i += stride) {
            int d = dst[i];
            if ((d >> 13) == p) {
                int pos = atomicAdd(&cursor[d], 1);
                ssrc[pos] = (ushort_t)src[i];
            }
        }
    }
}

// GEMM: out_bf16[N x FOUT] = in[N x 128] @ W[128 x FOUT]; W staged in LDS.
template<int FOUT>
__global__ __launch_bounds__(256) void k_gemm(const float* __restrict__ in,
                                              const float* __restrict__ W,
                                              ushort_t* __restrict__ out, int n) {
    __shared__ float Ws[128 * FOUT];
    __shared__ float Xs[32][129];
    const int tid = threadIdx.x;
    const int row0 = blockIdx.x * 32;

    for (int i = tid; i < 128 * FOUT / 4; i += 256)
        ((float4*)Ws)[i] = ((const float4*)W)[i];

    for (int i = tid; i < 1024; i += 256) {
        int r = i >> 5;
        int c = (i & 31) << 2;
        int gr = row0 + r;
        float4 v = make_float4(0.f, 0.f, 0.f, 0.f);
        if (gr < n) v = *(const float4*)(in + (size_t)gr * 128 + c);
        Xs[r][c + 0] = v.x; Xs[r][c + 1] = v.y;
        Xs[r][c + 2] = v.z; Xs[r][c + 3] = v.w;
    }
    __syncthreads();

    if constexpr (FOUT == 128) {
        const int tc = (tid & 15) * 8;
        const int tr = (tid >> 4) * 2;
        float acc0[8] = {0,0,0,0,0,0,0,0};
        float acc1[8] = {0,0,0,0,0,0,0,0};
        for (int k = 0; k < 128; ++k) {
            float a0 = Xs[tr][k];
            float a1 = Xs[tr + 1][k];
            float4 b0 = *(const float4*)&Ws[k * 128 + tc];
            float4 b1 = *(const float4*)&Ws[k * 128 + tc + 4];
            acc0[0] += a0 * b0.x; acc0[1] += a0 * b0.y;
            acc0[2] += a0 * b0.z; acc0[3] += a0 * b0.w;
            acc0[4] += a0 * b1.x; acc0[5] += a0 * b1.y;
            acc0[6] += a0 * b1.z; acc0[7] += a0 * b1.w;
            acc1[0] += a1 * b0.x; acc1[1] += a1 * b0.y;
            acc1[2] += a1 * b0.z; acc1[3] += a1 * b0.w;
            acc1[4] += a1 * b1.x; acc1[5] += a1 * b1.y;
            acc1[6] += a1 * b1.z; acc1[7] += a1 * b1.w;
        }
        int gr = row0 + tr;
        if (gr < n) {
            uint4 o;
            o.x = (unsigned)f2bf(acc0[0]) | ((unsigned)f2bf(acc0[1]) << 16);
            o.y = (unsigned)f2bf(acc0[2]) | ((unsigned)f2bf(acc0[3]) << 16);
            o.z = (unsigned)f2bf(acc0[4]) | ((unsigned)f2bf(acc0[5]) << 16);
            o.w = (unsigned)f2bf(acc0[6]) | ((unsigned)f2bf(acc0[7]) << 16);
            *(uint4*)(out + (size_t)gr * 128 + tc) = o;
        }
        if (gr + 1 < n) {
            uint4 o;
            o.x = (unsigned)f2bf(acc1[0]) | ((unsigned)f2bf(acc1[1]) << 16);
            o.y = (unsigned)f2bf(acc1[2]) | ((unsigned)f2bf(acc1[3]) << 16);
            o.z = (unsigned)f2bf(acc1[4]) | ((unsigned)f2bf(acc1[5]) << 16);
            o.w = (unsigned)f2bf(acc1[6]) | ((unsigned)f2bf(acc1[7]) << 16);
            *(uint4*)(out + (size_t)(gr + 1) * 128 + tc) = o;
        }
    } else {
        const int tc = (tid & 7) * 5;
        const int tr = tid >> 3;
        float acc[5] = {0,0,0,0,0};
        for (int k = 0; k < 128; ++k) {
            float a = Xs[tr][k];
            #pragma unroll
            for (int j = 0; j < 5; ++j) acc[j] += a * Ws[k * 40 + tc + j];
        }
        int gr = row0 + tr;
        if (gr < n) {
            #pragma unroll
            for (int j = 0; j < 5; ++j) out[(size_t)gr * 40 + tc + j] = f2bf(acc[j]);
        }
    }
}

// CSR aggregation, 128 bf16 features: one wave per dst node, lane owns 2.
// ag_fp32[d] = (sum_s hb[s]*dinv[s] + hb[d]*dinv[d]) * dinv[d] + b  (+ReLU)
template<bool RELU>
__global__ __launch_bounds__(256) void k_agg128(const int* __restrict__ row_start,
                                                const int* __restrict__ row_end,
                                                const ushort_t* __restrict__ hb,
                                                const float* __restrict__ dinv,
                                                const float* __restrict__ bias,
                                                const ushort_t* __restrict__ ssrc,
                                                float* __restrict__ ag, int n) {
    const int wid = (blockIdx.x * 256 + threadIdx.x) >> 6;
    const int lane = threadIdx.x & 63;
    if (wid >= n) return;
    const int d = wid;
    const int beg = row_start[d];
    const int end = row_end[d];
    const unsigned int* hu = (const unsigned int*)hb;   // 2 bf16 per u32

    float ax = 0.f, ay = 0.f;
    int i = beg;
    for (; i + 2 <= end; i += 2) {
        int s0 = ssrc[i];
        int s1 = ssrc[i + 1];
        float w0 = dinv[s0];
        float w1 = dinv[s1];
        unsigned int u0 = hu[s0 * 64 + lane];
        unsigned int u1 = hu[s1 * 64 + lane];
        ax += __uint_as_float(u0 << 16) * w0 + __uint_as_float(u1 << 16) * w1;
        ay += __uint_as_float(u0 & 0xFFFF0000u) * w0 + __uint_as_float(u1 & 0xFFFF0000u) * w1;
    }
    if (i < end) {
        int s = ssrc[i];
        float w = dinv[s];
        unsigned int u = hu[s * 64 + lane];
        ax += __uint_as_float(u << 16) * w;
        ay += __uint_as_float(u & 0xFFFF0000u) * w;
    }
    const float dd = dinv[d];
    unsigned int ud = hu[d * 64 + lane];
    const int f = lane * 2;
    float ox = (ax + __uint_as_float(ud << 16) * dd) * dd + bias[f];
    float oy = (ay + __uint_as_float(ud & 0xFFFF0000u) * dd) * dd + bias[f + 1];
    if (RELU) { ox = fmaxf(ox, 0.f); oy = fmaxf(oy, 0.f); }
    *(float2*)(ag + (size_t)d * 128 + f) = make_float2(ox, oy);
}

// CSR aggregation, 40 bf16 features + fused log_softmax. Wave/node, lanes 0..39.
__global__ __launch_bounds__(256) void k_agg40_lsm(const int* __restrict__ row_start,
                                                   const int* __restrict__ row_end,
                                                   const ushort_t* __restrict__ hb,
                                                   const float* __restrict__ dinv,
                                                   const float* __restrict__ bias,
                                                   const ushort_t* __restrict__ ssrc,
                                                   float* __restrict__ out, int n) {
    const int wid = (blockIdx.x * 256 + threadIdx.x) >> 6;
    const int lane = threadIdx.x & 63;
    if (wid >= n) return;
    const int d = wid;
    const int beg = row_start[d];
    const int end = row_end[d];
    const bool act = lane < 40;
    const int f = act ? lane : 0;

    float acc = 0.f;
    int i = beg;
    for (; i + 2 <= end; i += 2) {
        int s0 = ssrc[i];
        int s1 = ssrc[i + 1];
        acc += bf2f(hb[(size_t)s0 * 40 + f]) * dinv[s0]
             + bf2f(hb[(size_t)s1 * 40 + f]) * dinv[s1];
    }
    if (i < end) {
        int s = ssrc[i];
        acc += bf2f(hb[(size_t)s * 40 + f]) * dinv[s];
    }
    const float dd = dinv[d];
    float v = (acc + bf2f(hb[(size_t)d * 40 + f]) * dd) * dd + bias[f];

    float m = act ? v : -3.4e38f;
    #pragma unroll
    for (int off = 32; off; off >>= 1) m = fmaxf(m, __shfl_xor(m, off, 64));
    float ex = act ? __expf(v - m) : 0.f;
    float s = ex;
    #pragma unroll
    for (int off = 32; off; off >>= 1) s += __shfl_xor(s, off, 64);
    if (act) out[(size_t)d * 40 + lane] = v - m - logf(s);
}

extern "C" void kernel_launch(void* const* d_in, const int* in_sizes, int n_in,
                              void* d_out, int out_size, void* d_ws, size_t ws_size,
                              hipStream_t stream) {
    const float* x  = (const float*)d_in[0];
    const int*   ei = (const int*)d_in[1];
    const float* W1 = (const float*)d_in[2];
    const float* b1 = (const float*)d_in[3];
    const float* W2 = (const float*)d_in[4];
    const float* b2 = (const float*)d_in[5];
    const float* W3 = (const float*)d_in[6];
    const float* b3 = (const float*)d_in[7];
    float* out = (float*)d_out;

    const int N = in_sizes[0] / 128;
    const int E = in_sizes[1] / 2;
    const int* src = ei;
    const int* dst = ei + E;

    // workspace layout (float-sized slots)
    float* ws = (float*)d_ws;
    const int NP = 50176;                                       // N padded
    float*    dinv      = ws;                                   // NP f32
    int*      hist      = (int*)(ws + NP);                      // NP i32
    int*      row_start = (int*)(ws + 2 * NP);                  // NP i32
    int*      cursor    = (int*)(ws + 3 * NP);                  // NP i32
    ushort_t* ssrc      = (ushort_t*)(ws + 4 * NP);             // E u16
    ushort_t* hb        = (ushort_t*)(ws + 4 * NP + (E + 2) / 2 + 64); // N*128 bf16
    float*    ag        = (float*)(hb + (size_t)NP * 128);      // N*128 f32

    const int gemm_grid = (N + 31) / 32;
    const int agg_grid = (N + 3) / 4;   // 4 waves (nodes) per 256-block

    // --- build CSR (dst-sorted) + degree norm ---
    hipMemsetAsync(hist, 0, (size_t)N * sizeof(int), stream);
    k_hist<<<1024, 256, 0, stream>>>(dst, hist, E);
    k_scan<<<1, 1024, 0, stream>>>(hist, row_start, cursor, dinv, N);
    k_scatter<<<1024, 256, 0, stream>>>(src, dst, cursor, ssrc, E);
    // cursor[i] now == row_end[i]

    // --- layer 1 ---
    k_gemm<128><<<gemm_grid, 256, 0, stream>>>(x, W1, hb, N);
    k_agg128<true><<<agg_grid, 256, 0, stream>>>(row_start, cursor, hb, dinv, b1, ssrc, ag, N);

    // --- layer 2 ---
    k_gemm<128><<<gemm_grid, 256, 0, stream>>>(ag, W2, hb, N);
    k_agg128<true><<<agg_grid, 256, 0, stream>>>(row_start, cursor, hb, dinv, b2, ssrc, ag, N);

    // --- layer 3 + log_softmax ---
    k_gemm<40><<<gemm_grid, 256, 0, stream>>>(ag, W3, hb, N);
    k_agg40_lsm<<<agg_grid, 256, 0, stream>>>(row_start, cursor, hb, dinv, b3, ssrc, out, N);
}

// Round 12
// 672.502 us; speedup vs baseline: 4.8069x; 1.1791x over previous
//
#include <hip/hip_runtime.h>
#include <cmath>

// ---------------------------------------------------------------------------
// GCN 3-layer forward on MI355X — round 11.
// vs round 10 (793us): k_scan (134us, single 1024-thread block, 0.14% occ,
// latency-bound) replaced by k_alloc: wave-aggregated atomic row allocation.
// CSR rows don't need ordered offsets — any disjoint allocation works, so
// in-wave shfl prefix + 1 atomicAdd per wave (~782 total) does it at full
// grid parallelism. Everything else unchanged from round 10.
// ---------------------------------------------------------------------------

typedef unsigned short ushort_t;

__device__ __forceinline__ ushort_t f2bf(float x) {
    unsigned int u = __float_as_uint(x);
    u += 0x7FFF + ((u >> 16) & 1);   // round-to-nearest-even
    return (ushort_t)(u >> 16);
}
__device__ __forceinline__ float bf2f(ushort_t b) {
    return __uint_as_float(((unsigned int)b) << 16);
}

__global__ void k_hist(const int* __restrict__ dst, int* __restrict__ hist, int e) {
    int i = blockIdx.x * blockDim.x + threadIdx.x;
    int stride = gridDim.x * blockDim.x;
    for (; i < e; i += stride) atomicAdd(&hist[dst[i]], 1);
}

// wave-aggregated row allocation: in-wave exclusive prefix of hist via shfl,
// one atomicAdd per wave on gcounter. Row placement order is arbitrary (valid:
// row_start is always looked up, never assumed sorted).
__global__ void k_alloc(const int* __restrict__ hist, int* __restrict__ gcounter,
                        int* __restrict__ row_start, int* __restrict__ cursor,
                        float* __restrict__ dinv, int n) {
    const int i = blockIdx.x * blockDim.x + threadIdx.x;
    const int lane = threadIdx.x & 63;
    int h = (i < n) ? hist[i] : 0;
    int pre = h;                              // inclusive prefix within wave
    #pragma unroll
    for (int off = 1; off < 64; off <<= 1) {
        int t = __shfl_up(pre, off, 64);
        if (lane >= off) pre += t;
    }
    int wavesum = __shfl(pre, 63, 64);
    int base = 0;
    if (lane == 63) base = atomicAdd(gcounter, wavesum);
    base = __shfl(base, 63, 64);
    if (i < n) {
        int rs = base + (pre - h);            // exclusive prefix
        row_start[i] = rs;
        cursor[i] = rs;
        dinv[i] = rsqrtf(1.0f + (float)h);
    }
}

// multi-pass scatter: pass p handles dst in [p*8192,(p+1)*8192) so concurrent
// ssrc writes are confined to a ~512KB window (L2 lines fill before eviction).
__global__ void k_scatter(const int* __restrict__ src, const int* __restrict__ dst,
                          int* __restrict__ cursor, ushort_t* __restrict__ ssrc, int e) {
    const int tid0 = blockIdx.x * blockDim.x + threadIdx.x;
    const int stride = gridDim.x * blockDim.x;
    for (int p = 0; p < 7; ++p) {          // 50000>>13 == 6, so passes 0..6
        for (int i = tid0; i < e; i += stride) {
            int d = dst[i];
            if ((d >> 13) == p) {
                int pos = atomicAdd(&cursor[d], 1);
                ssrc[pos] = (ushort_t)src[i];
            }
        }
    }
}

// GEMM: out_bf16[N x FOUT] = in[N x 128] @ W[128 x FOUT]; W staged in LDS.
template<int FOUT>
__global__ __launch_bounds__(256) void k_gemm(const float* __restrict__ in,
                                              const float* __restrict__ W,
                                              ushort_t* __restrict__ out, int n) {
    __shared__ float Ws[128 * FOUT];
    __shared__ float Xs[32][129];
    const int tid = threadIdx.x;
    const int row0 = blockIdx.x * 32;

    for (int i = tid; i < 128 * FOUT / 4; i += 256)
        ((float4*)Ws)[i] = ((const float4*)W)[i];

    for (int i = tid; i < 1024; i += 256) {
        int r = i >> 5;
        int c = (i & 31) << 2;
        int gr = row0 + r;
        float4 v = make_float4(0.f, 0.f, 0.f, 0.f);
        if (gr < n) v = *(const float4*)(in + (size_t)gr * 128 + c);
        Xs[r][c + 0] = v.x; Xs[r][c + 1] = v.y;
        Xs[r][c + 2] = v.z; Xs[r][c + 3] = v.w;
    }
    __syncthreads();

    if constexpr (FOUT == 128) {
        const int tc = (tid & 15) * 8;
        const int tr = (tid >> 4) * 2;
        float acc0[8] = {0,0,0,0,0,0,0,0};
        float acc1[8] = {0,0,0,0,0,0,0,0};
        for (int k = 0; k < 128; ++k) {
            float a0 = Xs[tr][k];
            float a1 = Xs[tr + 1][k];
            float4 b0 = *(const float4*)&Ws[k * 128 + tc];
            float4 b1 = *(const float4*)&Ws[k * 128 + tc + 4];
            acc0[0] += a0 * b0.x; acc0[1] += a0 * b0.y;
            acc0[2] += a0 * b0.z; acc0[3] += a0 * b0.w;
            acc0[4] += a0 * b1.x; acc0[5] += a0 * b1.y;
            acc0[6] += a0 * b1.z; acc0[7] += a0 * b1.w;
            acc1[0] += a1 * b0.x; acc1[1] += a1 * b0.y;
            acc1[2] += a1 * b0.z; acc1[3] += a1 * b0.w;
            acc1[4] += a1 * b1.x; acc1[5] += a1 * b1.y;
            acc1[6] += a1 * b1.z; acc1[7] += a1 * b1.w;
        }
        int gr = row0 + tr;
        if (gr < n) {
            uint4 o;
            o.x = (unsigned)f2bf(acc0[0]) | ((unsigned)f2bf(acc0[1]) << 16);
            o.y = (unsigned)f2bf(acc0[2]) | ((unsigned)f2bf(acc0[3]) << 16);
            o.z = (unsigned)f2bf(acc0[4]) | ((unsigned)f2bf(acc0[5]) << 16);
            o.w = (unsigned)f2bf(acc0[6]) | ((unsigned)f2bf(acc0[7]) << 16);
            *(uint4*)(out + (size_t)gr * 128 + tc) = o;
        }
        if (gr + 1 < n) {
            uint4 o;
            o.x = (unsigned)f2bf(acc1[0]) | ((unsigned)f2bf(acc1[1]) << 16);
            o.y = (unsigned)f2bf(acc1[2]) | ((unsigned)f2bf(acc1[3]) << 16);
            o.z = (unsigned)f2bf(acc1[4]) | ((unsigned)f2bf(acc1[5]) << 16);
            o.w = (unsigned)f2bf(acc1[6]) | ((unsigned)f2bf(acc1[7]) << 16);
            *(uint4*)(out + (size_t)(gr + 1) * 128 + tc) = o;
        }
    } else {
        const int tc = (tid & 7) * 5;
        const int tr = tid >> 3;
        float acc[5] = {0,0,0,0,0};
        for (int k = 0; k < 128; ++k) {
            float a = Xs[tr][k];
            #pragma unroll
            for (int j = 0; j < 5; ++j) acc[j] += a * Ws[k * 40 + tc + j];
        }
        int gr = row0 + tr;
        if (gr < n) {
            #pragma unroll
            for (int j = 0; j < 5; ++j) out[(size_t)gr * 40 + tc + j] = f2bf(acc[j]);
        }
    }
}

// CSR aggregation, 128 bf16 features: one wave per dst node, lane owns 2.
// ag_fp32[d] = (sum_s hb[s]*dinv[s] + hb[d]*dinv[d]) * dinv[d] + b  (+ReLU)
template<bool RELU>
__global__ __launch_bounds__(256) void k_agg128(const int* __restrict__ row_start,
                                                const int* __restrict__ row_end,
                                                const ushort_t* __restrict__ hb,
                                                const float* __restrict__ dinv,
                                                const float* __restrict__ bias,
                                                const ushort_t* __restrict__ ssrc,
                                                float* __restrict__ ag, int n) {
    const int wid = (blockIdx.x * 256 + threadIdx.x) >> 6;
    const int lane = threadIdx.x & 63;
    if (wid >= n) return;
    const int d = wid;
    const int beg = row_start[d];
    const int end = row_end[d];
    const unsigned int* hu = (const unsigned int*)hb;   // 2 bf16 per u32

    float ax = 0.f, ay = 0.f;
    int i = beg;
    for (; i + 2 <= end; i += 2) {
        int s0 = ssrc[i];
        int s1 = ssrc[i + 1];
        float w0 = dinv[s0];
        float w1 = dinv[s1];
        unsigned int u0 = hu[s0 * 64 + lane];
        unsigned int u1 = hu[s1 * 64 + lane];
        ax += __uint_as_float(u0 << 16) * w0 + __uint_as_float(u1 << 16) * w1;
        ay += __uint_as_float(u0 & 0xFFFF0000u) * w0 + __uint_as_float(u1 & 0xFFFF0000u) * w1;
    }
    if (i < end) {
        int s = ssrc[i];
        float w = dinv[s];
        unsigned int u = hu[s * 64 + lane];
        ax += __uint_as_float(u << 16) * w;
        ay += __uint_as_float(u & 0xFFFF0000u) * w;
    }
    const float dd = dinv[d];
    unsigned int ud = hu[d * 64 + lane];
    const int f = lane * 2;
    float ox = (ax + __uint_as_float(ud << 16) * dd) * dd + bias[f];
    float oy = (ay + __uint_as_float(ud & 0xFFFF0000u) * dd) * dd + bias[f + 1];
    if (RELU) { ox = fmaxf(ox, 0.f); oy = fmaxf(oy, 0.f); }
    *(float2*)(ag + (size_t)d * 128 + f) = make_float2(ox, oy);
}

// CSR aggregation, 40 bf16 features + fused log_softmax. Wave/node, lanes 0..39.
__global__ __launch_bounds__(256) void k_agg40_lsm(const int* __restrict__ row_start,
                                                   const int* __restrict__ row_end,
                                                   const ushort_t* __restrict__ hb,
                                                   const float* __restrict__ dinv,
                                                   const float* __restrict__ bias,
                                                   const ushort_t* __restrict__ ssrc,
                                                   float* __restrict__ out, int n) {
    const int wid = (blockIdx.x * 256 + threadIdx.x) >> 6;
    const int lane = threadIdx.x & 63;
    if (wid >= n) return;
    const int d = wid;
    const int beg = row_start[d];
    const int end = row_end[d];
    const bool act = lane < 40;
    const int f = act ? lane : 0;

    float acc = 0.f;
    int i = beg;
    for (; i + 2 <= end; i += 2) {
        int s0 = ssrc[i];
        int s1 = ssrc[i + 1];
        acc += bf2f(hb[(size_t)s0 * 40 + f]) * dinv[s0]
             + bf2f(hb[(size_t)s1 * 40 + f]) * dinv[s1];
    }
    if (i < end) {
        int s = ssrc[i];
        acc += bf2f(hb[(size_t)s * 40 + f]) * dinv[s];
    }
    const float dd = dinv[d];
    float v = (acc + bf2f(hb[(size_t)d * 40 + f]) * dd) * dd + bias[f];

    float m = act ? v : -3.4e38f;
    #pragma unroll
    for (int off = 32; off; off >>= 1) m = fmaxf(m, __shfl_xor(m, off, 64));
    float ex = act ? __expf(v - m) : 0.f;
    float s = ex;
    #pragma unroll
    for (int off = 32; off; off >>= 1) s += __shfl_xor(s, off, 64);
    if (act) out[(size_t)d * 40 + lane] = v - m - logf(s);
}

extern "C" void kernel_launch(void* const* d_in, const int* in_sizes, int n_in,
                              void* d_out, int out_size, void* d_ws, size_t ws_size,
                              hipStream_t stream) {
    const float* x  = (const float*)d_in[0];
    const int*   ei = (const int*)d_in[1];
    const float* W1 = (const float*)d_in[2];
    const float* b1 = (const float*)d_in[3];
    const float* W2 = (const float*)d_in[4];
    const float* b2 = (const float*)d_in[5];
    const float* W3 = (const float*)d_in[6];
    const float* b3 = (const float*)d_in[7];
    float* out = (float*)d_out;

    const int N = in_sizes[0] / 128;
    const int E = in_sizes[1] / 2;
    const int* src = ei;
    const int* dst = ei + E;

    // workspace layout (float-sized slots)
    float* ws = (float*)d_ws;
    const int NP = 50176;                                       // N padded
    float*    dinv      = ws;                                   // NP f32
    int*      hist      = (int*)(ws + NP);                      // NP i32 (tail slot = gcounter)
    int*      row_start = (int*)(ws + 2 * NP);                  // NP i32
    int*      cursor    = (int*)(ws + 3 * NP);                  // NP i32
    ushort_t* ssrc      = (ushort_t*)(ws + 4 * NP);             // E u16
    ushort_t* hb        = (ushort_t*)(ws + 4 * NP + (E + 2) / 2 + 64); // N*128 bf16
    float*    ag        = (float*)(hb + (size_t)NP * 128);      // N*128 f32

    int* gcounter = hist + NP - 1;   // unused histogram slot (NP-1 >= N), zeroed below

    const int nblk = (N + 255) / 256;
    const int gemm_grid = (N + 31) / 32;
    const int agg_grid = (N + 3) / 4;   // 4 waves (nodes) per 256-block

    // --- build CSR (dst-sorted) + degree norm ---
    hipMemsetAsync(hist, 0, (size_t)NP * sizeof(int), stream);  // hist + gcounter
    k_hist<<<1024, 256, 0, stream>>>(dst, hist, E);
    k_alloc<<<nblk, 256, 0, stream>>>(hist, gcounter, row_start, cursor, dinv, N);
    k_scatter<<<1024, 256, 0, stream>>>(src, dst, cursor, ssrc, E);
    // cursor[i] now == row_end[i]

    // --- layer 1 ---
    k_gemm<128><<<gemm_grid, 256, 0, stream>>>(x, W1, hb, N);
    k_agg128<true><<<agg_grid, 256, 0, stream>>>(row_start, cursor, hb, dinv, b1, ssrc, ag, N);

    // --- layer 2 ---
    k_gemm<128><<<gemm_grid, 256, 0, stream>>>(ag, W2, hb, N);
    k_agg128<true><<<agg_grid, 256, 0, stream>>>(row_start, cursor, hb, dinv, b2, ssrc, ag, N);

    // --- layer 3 + log_softmax ---
    k_gemm<40><<<gemm_grid, 256, 0, stream>>>(ag, W3, hb, N);
    k_agg40_lsm<<<agg_grid, 256, 0, stream>>>(row_start, cursor, hb, dinv, b3, ssrc, out, N);
}